// Round 7
// baseline (515.307 us; speedup 1.0000x reference)
//
#include <hip/hip_runtime.h>
#include <hip/hip_fp16.h>

namespace {
constexpr int kT = 32, kDQ = 128, kK = 8, kD = 257, kCTX = 16;
constexpr float kDT = 0.2f, kDAMP = 0.1f, kGAMMA = 10.0f, kEPS = 1e-8f;

typedef _Float16 h2 __attribute__((ext_vector_type(2)));
typedef __fp16 fp16x2 __attribute__((ext_vector_type(2)));

__device__ __forceinline__ unsigned pk16(float lo, float hi) {
  fp16x2 r = __builtin_amdgcn_cvt_pkrtz(lo, hi);
  return __builtin_bit_cast(unsigned, r);
}
__device__ __forceinline__ float dot2(unsigned a, unsigned b, float c) {
#if __has_builtin(__builtin_amdgcn_fdot2)
  return __builtin_amdgcn_fdot2(__builtin_bit_cast(h2, a), __builtin_bit_cast(h2, b), c, false);
#else
  h2 ha = __builtin_bit_cast(h2, a), hb = __builtin_bit_cast(h2, b);
  return c + (float)ha.x * (float)hb.x + (float)ha.y * (float)hb.y;
#endif
}
__device__ __forceinline__ float fast_tanh(float x) {
  float e = __expf(2.f * x);
  return 1.f - 2.f / (e + 1.f);
}
}  // namespace

extern "C" __global__ void __launch_bounds__(512, 2)
seq_main(const int* __restrict__ inputs, const int* __restrict__ targets,
         const int* __restrict__ task_ids, const float* __restrict__ st0,
         const float* __restrict__ bit_emb, const float* __restrict__ task_u,
         const float* __restrict__ ctx_emb, const float* __restrict__ rw_g,
         const float* __restrict__ rb_g, const float* __restrict__ Wq_g,
         const float* __restrict__ Wc_g, const float* __restrict__ b_g,
         const float* __restrict__ A_g, float* __restrict__ wsout) {
  const int tid = threadIdx.x, b = blockIdx.x;
  const int w = tid >> 6, lane = tid & 63;
  const int k = lane >> 3, il = lane & 7;
  const int i0 = 8 * w + il;                 // row0; row1 = i0 + 64

  __shared__ __align__(16) unsigned tq_l[2][64];    // tanh(q) fp16, ping-pong
  __shared__ __align__(16) unsigned q16_l[2][64];   // q fp16, ping-pong
  __shared__ __align__(16) unsigned p16_l[64];      // p fp16 at e==7
  __shared__ __align__(16) unsigned rw16_l[32][132];// readout fp16 (dims 0..255), padded
  __shared__ __align__(16) float u4_l[4][kDQ];
  __shared__ float rws_l[32], rb_l[32];
  __shared__ float chartw_l[kK], cwnext_l[kK];
  __shared__ float lk_l[32];
  __shared__ float acc_l[64];
  __shared__ int task_l[kT], sel_l[kT], tgt_l[kT];

  // ---------------- init ----------------
  if (tid < 64) acc_l[tid] = 0.f;
  if (tid < 32) { rws_l[tid] = rw_g[tid * kD + 256]; rb_l[tid] = rb_g[tid]; }
  if (tid >= 64 && tid < 96) {
    int t = tid - 64;
    int bit = inputs[b * kT + t];
    int task = task_ids[b * kT + t];
    task_l[t] = task; sel_l[t] = task * 2 + bit; tgt_l[t] = targets[b * kT + t];
  }
  {
    int cb = tid >> 7, i = tid & 127;  // 512 = 4 combos x 128
    u4_l[cb][i] = tanhf(bit_emb[(cb & 1) * kDQ + i]) + tanhf(task_u[(cb >> 1) * kDQ + i]);
  }
  for (int idx = tid; idx < 32 * 128; idx += 512) {
    int pr = idx >> 7, dw = idx & 127;
    rw16_l[pr][dw] = pk16(rw_g[pr * kD + 2 * dw], rw_g[pr * kD + 2 * dw + 1]);
  }

  // A rows -> registers (fp16 packed)
  unsigned a0_[64], a1_[64];
  {
    const float4* r0 = (const float4*)(A_g + ((size_t)(k * kDQ + i0)) * kDQ);
    const float4* r1 = (const float4*)(A_g + ((size_t)(k * kDQ + i0 + 64)) * kDQ);
    #pragma unroll
    for (int jj = 0; jj < 32; ++jj) {
      float4 f = r0[jj];
      a0_[2 * jj] = pk16(f.x, f.y); a0_[2 * jj + 1] = pk16(f.z, f.w);
      f = r1[jj];
      a1_[2 * jj] = pk16(f.x, f.y); a1_[2 * jj + 1] = pk16(f.z, f.w);
    }
  }
  // Wq slice (fp16): j = 16*il .. 16*il+15, column k
  unsigned wqh[8];
  #pragma unroll
  for (int m = 0; m < 8; ++m)
    wqh[m] = pk16(Wq_g[(16 * il + 2 * m) * kK + k], Wq_g[(16 * il + 2 * m + 1) * kK + k]);
  // ctx terms for this lane's k
  float ctx0k = b_g[k], ctx1k = b_g[k];
  #pragma unroll
  for (int c = 0; c < kCTX; ++c) {
    float wc = Wc_g[c * kK + k];
    ctx0k += tanhf(ctx_emb[c]) * wc;
    ctx1k += tanhf(ctx_emb[kCTX + c]) * wc;
  }
  const float s_f = st0[b * kD + 256];

  // persistent state (redundant across k-groups)
  float q0 = st0[b * kD + i0],        p0 = st0[b * kD + kDQ + i0];
  float q1 = st0[b * kD + i0 + 64],   p1 = st0[b * kD + kDQ + i0 + 64];
  {
    float tv0 = fast_tanh(q0), tv1 = fast_tanh(q1);
    float qo0 = __shfl_xor(q0, 1), qo1 = __shfl_xor(q1, 1);
    float to0 = __shfl_xor(tv0, 1), to1 = __shfl_xor(tv1, 1);
    if (lane < 8 && !(il & 1)) {
      int dw = 4 * w + (il >> 1);
      q16_l[0][dw] = pk16(q0, qo0);       tq_l[0][dw] = pk16(tv0, to0);
      q16_l[0][32 + dw] = pk16(q1, qo1);  tq_l[0][32 + dw] = pk16(tv1, to1);
    }
  }
  float u0 = 0.f, u1 = 0.f;
  __syncthreads();

  // ---- decode helper: logits_k = state16 . rw16 (reads q16[0], p16) ----
  auto runDecode = [&]() {
    int pair = tid >> 4, ln = tid & 15;
    uint4 sa, sb;
    if (ln < 8) {
      sa = ((const uint4*)q16_l[0])[2 * ln]; sb = ((const uint4*)q16_l[0])[2 * ln + 1];
    } else {
      sa = ((const uint4*)p16_l)[2 * (ln - 8)]; sb = ((const uint4*)p16_l)[2 * (ln - 8) + 1];
    }
    uint4 ra = ((const uint4*)&rw16_l[pair][0])[2 * ln];
    uint4 rb2 = ((const uint4*)&rw16_l[pair][0])[2 * ln + 1];
    float d = 0.f;
    d = dot2(sa.x, ra.x, d); d = dot2(sa.y, ra.y, d);
    d = dot2(sa.z, ra.z, d); d = dot2(sa.w, ra.w, d);
    d = dot2(sb.x, rb2.x, d); d = dot2(sb.y, rb2.y, d);
    d = dot2(sb.z, rb2.z, d); d = dot2(sb.w, rb2.w, d);
    if (ln == 0) d += s_f * rws_l[pair];
    d += __shfl_xor(d, 1); d += __shfl_xor(d, 2);
    d += __shfl_xor(d, 4); d += __shfl_xor(d, 8);
    if (ln == 0) lk_l[pair] = d + rb_l[pair];
  };

  // ---- tail: scalar per-t losses (tid 0 ONLY — LDS accumulators) ----
  auto runTail = [&](int t) {
    if (tid != 0) return;   // <<< r6 bug fix: was unguarded -> 512-thread RMW race
    const int tgt = tgt_l[t];
    const int task = task_l[t];
    const int prv = (t == 0) ? 0 : tgt_l[t - 1];
    float cw[kK], ch[kK];
    #pragma unroll
    for (int kk = 0; kk < kK; ++kk) { cw[kk] = cwnext_l[kk]; ch[kk] = chartw_l[kk]; }
    int i0_ = 0; float v0 = cw[0];
    #pragma unroll
    for (int kk = 1; kk < kK; ++kk) if (cw[kk] > v0) { v0 = cw[kk]; i0_ = kk; }
    int i1_ = (i0_ == 0) ? 1 : 0; float v1 = (i0_ == 0) ? cw[1] : cw[0];
    #pragma unroll
    for (int kk = 0; kk < kK; ++kk) if (kk != i0_ && cw[kk] > v1) { v1 = cw[kk]; i1_ = kk; }
    float wsum = fmaxf(v0 + v1, kEPS);
    float wn0 = v0 / wsum, wn1 = v1 / wsum;
    float lg4[4];
    #pragma unroll
    for (int v = 0; v < 4; ++v) lg4[v] = wn0 * lk_l[i0_ * 4 + v] + wn1 * lk_l[i1_ * 4 + v];
    float m2 = fmaxf(lg4[0], lg4[1]);
    float lse2 = m2 + logf(expf(lg4[0] - m2) + expf(lg4[1] - m2));
    float m4 = fmaxf(fmaxf(lg4[0], lg4[1]), fmaxf(lg4[2], lg4[3]));
    float lse4 = m4 + logf(expf(lg4[0] - m4) + expf(lg4[1] - m4) +
                           expf(lg4[2] - m4) + expf(lg4[3] - m4));
    int idx2 = (tgt < 1) ? tgt : 1;
    float p2 = (idx2 == 0) ? lg4[0] : lg4[1];
    float p4v = (tgt == 0) ? lg4[0] : ((tgt == 1) ? lg4[1] : ((tgt == 2) ? lg4[2] : lg4[3]));
    float pe = (task == 0) ? (lse2 - p2) : (lse4 - p4v);
    int pred;
    if (task == 0) pred = (lg4[1] > lg4[0]) ? 1 : 0;
    else {
      pred = 0; float bv = lg4[0];
      if (lg4[1] > bv) { bv = lg4[1]; pred = 1; }
      if (lg4[2] > bv) { bv = lg4[2]; pred = 2; }
      if (lg4[3] > bv) { bv = lg4[3]; pred = 3; }
    }
    float corr = (pred == tgt) ? 1.f : 0.f;
    float csl = -logf(fmaxf(ch[prv], kEPS));
    acc_l[0] += kGAMMA * (pe + csl); acc_l[1] += corr; acc_l[2] += pe;
    #pragma unroll
    for (int kk = 0; kk < kK; ++kk) acc_l[3 + kk] += ch[kk];
    acc_l[11 + task] += corr; acc_l[13 + task] += 1.f;
    if (task == 1) {
      #pragma unroll
      for (int kk = 0; kk < kK; ++kk) acc_l[15 + prv * kK + kk] += ch[kk];
      acc_l[47 + prv] += 1.f;
    }
  };

  // ---------------- main serial loop: 256 evo steps, 1 barrier each ----------------
  #pragma unroll 1
  for (int s = 0; s < 256; ++s) {
    const int cb = s & 1, nb = cb ^ 1;
    const int e = s & 7, t = s >> 3;

    // router logits: rl(k) = q . Wq[:,k]  (fp16 dot2, distributed over il)
    uint4 qa = ((const uint4*)q16_l[cb])[2 * il];
    uint4 qb = ((const uint4*)q16_l[cb])[2 * il + 1];
    float rl = 0.f;
    rl = dot2(wqh[0], qa.x, rl); rl = dot2(wqh[1], qa.y, rl);
    rl = dot2(wqh[2], qa.z, rl); rl = dot2(wqh[3], qa.w, rl);
    rl = dot2(wqh[4], qb.x, rl); rl = dot2(wqh[5], qb.y, rl);
    rl = dot2(wqh[6], qb.z, rl); rl = dot2(wqh[7], qb.w, rl);
    rl += __shfl_xor(rl, 1); rl += __shfl_xor(rl, 2); rl += __shfl_xor(rl, 4);

    if (e == 0) {
      if (s != 0) {
        // chart_w_next for t-1: same rl (state after t-1's evo), ctx of t-1
        float lgp = rl + (task_l[t - 1] ? ctx1k : ctx0k);
        float mxp = lgp;
        mxp = fmaxf(mxp, __shfl_xor(mxp, 8));
        mxp = fmaxf(mxp, __shfl_xor(mxp, 16));
        mxp = fmaxf(mxp, __shfl_xor(mxp, 32));
        float exp_ = __expf(lgp - mxp);
        float smp = exp_;
        smp += __shfl_xor(smp, 8); smp += __shfl_xor(smp, 16); smp += __shfl_xor(smp, 32);
        if (w == 0 && il == 0) cwnext_l[k] = exp_ / smp;
        runDecode();
      }
      int sel = sel_l[t];
      u0 = u4_l[sel][i0]; u1 = u4_l[sel][i0 + 64];
    }
    if (e == 1 && s > 8) runTail(t - 1);  // tid0-only (guarded inside)

    // softmax over k for this step's w
    float lg = rl + (task_l[t] ? ctx1k : ctx0k);
    float mx = lg;
    mx = fmaxf(mx, __shfl_xor(mx, 8));
    mx = fmaxf(mx, __shfl_xor(mx, 16));
    mx = fmaxf(mx, __shfl_xor(mx, 32));
    float ex = __expf(lg - mx);
    float sm = ex;
    sm += __shfl_xor(sm, 8); sm += __shfl_xor(sm, 16); sm += __shfl_xor(sm, 32);
    float wk = ex / sm;
    if (e == 7 && w == 0 && il == 0) chartw_l[k] = wk;  // ws[-1]

    // force: Y = A_row . tanh(q), then w-weighted xor-reduce over k
    float y0a = 0.f, y0b = 0.f, y0c = 0.f, y0d = 0.f;
    float y1a = 0.f, y1b = 0.f, y1c = 0.f, y1d = 0.f;
    const uint4* tq4 = (const uint4*)tq_l[cb];
    #pragma unroll
    for (int jj = 0; jj < 16; ++jj) {
      uint4 tt = tq4[jj];
      y0a = dot2(a0_[4 * jj + 0], tt.x, y0a); y0b = dot2(a0_[4 * jj + 1], tt.y, y0b);
      y0c = dot2(a0_[4 * jj + 2], tt.z, y0c); y0d = dot2(a0_[4 * jj + 3], tt.w, y0d);
      y1a = dot2(a1_[4 * jj + 0], tt.x, y1a); y1b = dot2(a1_[4 * jj + 1], tt.y, y1b);
      y1c = dot2(a1_[4 * jj + 2], tt.z, y1c); y1d = dot2(a1_[4 * jj + 3], tt.w, y1d);
    }
    float f0 = wk * ((y0a + y0b) + (y0c + y0d));
    float f1 = wk * ((y1a + y1b) + (y1c + y1d));
    f0 += __shfl_xor(f0, 8); f0 += __shfl_xor(f0, 16); f0 += __shfl_xor(f0, 32);
    f1 += __shfl_xor(f1, 8); f1 += __shfl_xor(f1, 16); f1 += __shfl_xor(f1, 32);

    // update (redundant across k-groups)
    float pn0 = (1.f - kDT * kDAMP) * p0 + kDT * (f0 + u0);
    float pn1 = (1.f - kDT * kDAMP) * p1 + kDT * (f1 + u1);
    q0 += kDT * fast_tanh(pn0); p0 = pn0;
    q1 += kDT * fast_tanh(pn1); p1 = pn1;
    float tv0 = fast_tanh(q0), tv1 = fast_tanh(q1);
    float qo0 = __shfl_xor(q0, 1), qo1 = __shfl_xor(q1, 1);
    float to0 = __shfl_xor(tv0, 1), to1 = __shfl_xor(tv1, 1);
    float po0 = __shfl_xor(p0, 1), po1 = __shfl_xor(p1, 1);
    if (lane < 8 && !(il & 1)) {
      int dw = 4 * w + (il >> 1);
      q16_l[nb][dw] = pk16(q0, qo0);       tq_l[nb][dw] = pk16(tv0, to0);
      q16_l[nb][32 + dw] = pk16(q1, qo1);  tq_l[nb][32 + dw] = pk16(tv1, to1);
      if (e == 7) {
        p16_l[dw] = pk16(p0, po0);
        p16_l[32 + dw] = pk16(p1, po1);
      }
    }
    __syncthreads();
  }

  // ---------------- epilogue: t = 31 ----------------
  {
    uint4 qa = ((const uint4*)q16_l[0])[2 * il];
    uint4 qb = ((const uint4*)q16_l[0])[2 * il + 1];
    float rl = 0.f;
    rl = dot2(wqh[0], qa.x, rl); rl = dot2(wqh[1], qa.y, rl);
    rl = dot2(wqh[2], qa.z, rl); rl = dot2(wqh[3], qa.w, rl);
    rl = dot2(wqh[4], qb.x, rl); rl = dot2(wqh[5], qb.y, rl);
    rl = dot2(wqh[6], qb.z, rl); rl = dot2(wqh[7], qb.w, rl);
    rl += __shfl_xor(rl, 1); rl += __shfl_xor(rl, 2); rl += __shfl_xor(rl, 4);
    float lgp = rl + (task_l[31] ? ctx1k : ctx0k);
    float mxp = lgp;
    mxp = fmaxf(mxp, __shfl_xor(mxp, 8));
    mxp = fmaxf(mxp, __shfl_xor(mxp, 16));
    mxp = fmaxf(mxp, __shfl_xor(mxp, 32));
    float exp_ = __expf(lgp - mxp);
    float smp = exp_;
    smp += __shfl_xor(smp, 8); smp += __shfl_xor(smp, 16); smp += __shfl_xor(smp, 32);
    if (w == 0 && il == 0) cwnext_l[k] = exp_ / smp;
    runDecode();
  }
  __syncthreads();
  runTail(31);
  __syncthreads();
  if (tid < 64) wsout[b * 64 + tid] = acc_l[tid];
}

extern "C" __global__ void seq_finalize(const float* __restrict__ ws, float* __restrict__ out) {
  const int tid = threadIdx.x;
  __shared__ float red[51];
  if (tid < 51) {
    float s = 0.f;
    for (int b = 0; b < 256; b++) s += ws[b * 64 + tid];
    red[tid] = s;
  }
  __syncthreads();
  if (tid == 0) {
    const float BT = 256.f * 32.f;
    out[0] = red[0] / BT;
    out[1] = red[1] / BT;
    out[2] = red[2] / BT;
    float us = 0.f;
    for (int k = 0; k < 8; k++) { out[3 + k] = red[3 + k]; us += red[3 + k]; }
    float ent = 0.f;
    for (int k = 0; k < 8; k++) {
      float dist = red[3 + k] / (us + kEPS);
      ent -= dist * logf(dist + kEPS);
    }
    out[11] = ent;
    out[12] = red[11] / (red[13] + kEPS);
    out[13] = red[12] / (red[14] + kEPS);
    float tot = 0.f;
    for (int j = 0; j < 32; j++) { out[14 + j] = red[15 + j]; tot += red[15 + j]; }
    for (int s2 = 0; s2 < 4; s2++) out[46 + s2] = red[47 + s2];
    float inv = 1.f / (tot + kEPS);
    float ps[4] = {0.f, 0.f, 0.f, 0.f};
    float pc[8] = {0.f, 0.f, 0.f, 0.f, 0.f, 0.f, 0.f, 0.f};
    for (int s2 = 0; s2 < 4; s2++)
      for (int k = 0; k < 8; k++) {
        float jv = red[15 + s2 * 8 + k] * inv;
        ps[s2] += jv; pc[k] += jv;
      }
    float mi = 0.f;
    for (int s2 = 0; s2 < 4; s2++)
      for (int k = 0; k < 8; k++) {
        float jv = red[15 + s2 * 8 + k] * inv;
        mi += jv * (logf(jv + kEPS) - logf(ps[s2] + kEPS) - logf(pc[k] + kEPS));
      }
    mi = (tot > 0.f) ? fmaxf(mi, 0.f) : 0.f;
    out[50] = mi;
  }
}

extern "C" void kernel_launch(void* const* d_in, const int* in_sizes, int n_in,
                              void* d_out, int out_size, void* d_ws, size_t ws_size,
                              hipStream_t stream) {
  (void)in_sizes; (void)n_in; (void)out_size; (void)ws_size;
  const int* inputs   = (const int*)d_in[0];
  const int* targets  = (const int*)d_in[1];
  const int* task_ids = (const int*)d_in[2];
  const float* st0      = (const float*)d_in[3];
  const float* bit_emb  = (const float*)d_in[4];
  const float* task_u   = (const float*)d_in[5];
  const float* ctx_emb  = (const float*)d_in[6];
  const float* rw       = (const float*)d_in[7];
  const float* rb       = (const float*)d_in[8];
  const float* Wq       = (const float*)d_in[9];
  const float* Wc       = (const float*)d_in[10];
  const float* bb       = (const float*)d_in[11];
  const float* A        = (const float*)d_in[12];
  float* ws  = (float*)d_ws;
  float* out = (float*)d_out;
  hipLaunchKernelGGL(seq_main, dim3(256), dim3(512), 0, stream,
                     inputs, targets, task_ids, st0, bit_emb, task_u, ctx_emb,
                     rw, rb, Wq, Wc, bb, A, ws);
  hipLaunchKernelGGL(seq_finalize, dim3(1), dim3(64), 0, stream, ws, out);
}